// Round 5
// baseline (242.396 us; speedup 1.0000x reference)
//
#include <hip/hip_runtime.h>
#include <cstdint>
#include <cstddef>

#define DEVI __device__ __forceinline__

typedef __bf16 bf16_t;
typedef __bf16 bf16x4 __attribute__((ext_vector_type(4)));
typedef __bf16 bf16x8 __attribute__((ext_vector_type(8)));
typedef float  f32x4  __attribute__((ext_vector_type(4)));
typedef float  f32x16 __attribute__((ext_vector_type(16)));
typedef unsigned short u16x4 __attribute__((ext_vector_type(4)));

static constexpr int Bz = 2, S = 2048, E = 1024, H = 16, Dh = 64;
static constexpr int M  = Bz * S;   // 4096 tokens
static constexpr int N  = H * Dh;   // 1024
static constexpr int Kd = E;        // 1024

DEVI unsigned short f2bf(float f) {
  unsigned u = __builtin_bit_cast(unsigned, f);
  return (unsigned short)((u + 0x7fffu + ((u >> 16) & 1u)) >> 16);
}

DEVI void async_copy16(void* lds, const void* g) {
  __builtin_amdgcn_global_load_lds((__attribute__((address_space(1))) void*)(g),
                                   (__attribute__((address_space(3))) void*)(lds), 16, 0, 0);
}

// ---------------- fused prep: convx | wtrans | rope table ----------------
__global__ void prep_kernel(const float* __restrict__ x, bf16_t* __restrict__ xb,
                            const float* __restrict__ Wq, const float* __restrict__ Wk,
                            const float* __restrict__ Wv, const float* __restrict__ Wo,
                            bf16_t* __restrict__ WtBase,
                            float* __restrict__ ropeC, float* __restrict__ ropeS) {
  __shared__ unsigned short tile[64][68];
  const int blk = blockIdx.x, tid = threadIdx.x;
  if (blk < 4096) {
    int i = blk * 256 + tid;
    float4 v = ((const float4*)x)[i];
    u16x4 o = { f2bf(v.x), f2bf(v.y), f2bf(v.z), f2bf(v.w) };
    ((u16x4*)xb)[i] = o;
  } else if (blk < 5120) {
    const int i = blk - 4096;
    const int z = i >> 8, rest = i & 255;
    const int n0 = (rest & 15) * 64, k0 = (rest >> 4) * 64;
    const float* W = (z == 0) ? Wq : (z == 1) ? Wk : (z == 2) ? Wv : Wo;
    unsigned short* T = (unsigned short*)(WtBase + (size_t)z * Kd * N);
    for (int e = tid; e < 1024; e += 256) {
      int r = e >> 4, c4 = (e & 15) * 4;
      float4 v = *(const float4*)(W + (size_t)(k0 + r) * N + n0 + c4);
      u16x4 o = { f2bf(v.x), f2bf(v.y), f2bf(v.z), f2bf(v.w) };
      *(u16x4*)&tile[r][c4] = o;
    }
    __syncthreads();
    for (int e = tid; e < 1024; e += 256) {
      int r = e >> 4, c4 = (e & 15) * 4;
      u16x4 o = { tile[c4][r], tile[c4 + 1][r], tile[c4 + 2][r], tile[c4 + 3][r] };
      *(u16x4*)&T[(size_t)(n0 + r) * Kd + k0 + c4] = o;
    }
  } else {
    int i = (blk - 5120) * 256 + tid;
    int pos = i >> 5, j = i & 31;
    float inv = exp2f(-(float)j * 0.41524101186092029f);   // log2(10000)/32
    float ang = (float)pos * inv;
    ropeC[i] = cosf(ang);
    ropeS[i] = sinf(ang);
  }
}

// bf16 [BH][S][D] -> bf16 [BH][D][S]
__global__ void vtrans_kernel(const bf16_t* __restrict__ V, bf16_t* __restrict__ Vt) {
  __shared__ unsigned short tile[64][68];
  const int bh = blockIdx.y;
  const int s0 = blockIdx.x * 64;
  const unsigned short* Vp = (const unsigned short*)V + (size_t)bh * S * Dh;
  unsigned short* Tp = (unsigned short*)Vt + (size_t)bh * Dh * S;
  const int tid = threadIdx.x;
  for (int e = tid; e < 1024; e += 256) {
    int r = e >> 4, c4 = (e & 15) * 4;
    u16x4 v = *(const u16x4*)(Vp + (size_t)(s0 + r) * Dh + c4);
    *(u16x4*)&tile[r][c4] = v;
  }
  __syncthreads();
  for (int e = tid; e < 1024; e += 256) {
    int d = e >> 4, s4 = (e & 15) * 4;
    u16x4 o = { tile[s4][d], tile[s4 + 1][d], tile[s4 + 2][d], tile[s4 + 3][d] };
    *(u16x4*)&Tp[(size_t)d * S + s0 + s4] = o;
  }
}

// ---------------- GEMM core (128x128 tile, BK=32, global_load_lds) ----------------

DEVI void gemm_mainloop(const bf16_t* __restrict__ A, const bf16_t* __restrict__ Bt,
                        bf16_t* sA, bf16_t* sB, int m0, int n0, f32x4 (&acc)[4][4]) {
  const int tid  = threadIdx.x;
  const int lane = tid & 63;
  const int wid  = tid >> 6;
  const int l16  = lane & 15;
  const int quad = lane >> 4;
  const int wm = (wid >> 1) * 64;
  const int wn = (wid & 1) * 64;
  const int o0 = wid * 2048 + lane * 16;   // byte offset within 8KB tile
  const int o1 = o0 + 1024;
  const int r0 = o0 >> 6, c0 = o0 & 63;
  const int r1 = o1 >> 6, c1 = o1 & 63;
  const char* Ab = (const char*)A;
  const char* Bb = (const char*)Bt;
  char* sAc = (char*)sA;
  char* sBc = (char*)sB;

  for (int k0 = 0; k0 < Kd; k0 += 32) {
    __syncthreads();
    async_copy16(sAc + wid * 2048,        Ab + ((size_t)(m0 + r0) * Kd + k0) * 2 + c0);
    async_copy16(sAc + wid * 2048 + 1024, Ab + ((size_t)(m0 + r1) * Kd + k0) * 2 + c1);
    async_copy16(sBc + wid * 2048,        Bb + ((size_t)(n0 + r0) * Kd + k0) * 2 + c0);
    async_copy16(sBc + wid * 2048 + 1024, Bb + ((size_t)(n0 + r1) * Kd + k0) * 2 + c1);
    __syncthreads();
    bf16x8 af[4], bfv[4];
#pragma unroll
    for (int mi = 0; mi < 4; ++mi)
      af[mi] = *(const bf16x8*)(sA + (wm + mi * 16 + l16) * 32 + quad * 8);
#pragma unroll
    for (int ni = 0; ni < 4; ++ni)
      bfv[ni] = *(const bf16x8*)(sB + (wn + ni * 16 + l16) * 32 + quad * 8);
#pragma unroll
    for (int mi = 0; mi < 4; ++mi)
#pragma unroll
      for (int ni = 0; ni < 4; ++ni)
        acc[mi][ni] = __builtin_amdgcn_mfma_f32_16x16x32_bf16(af[mi], bfv[ni], acc[mi][ni], 0, 0, 0);
  }
}

// z = 0:Q(RoPE+scale) 1:K(RoPE) 2:V ; out layout [B,H,S,D] bf16
__global__ __launch_bounds__(256, 3) void gemm_qkv_kernel(
    const bf16_t* __restrict__ xb, const bf16_t* __restrict__ WtBase,
    const float* __restrict__ bq, const float* __restrict__ bk, const float* __restrict__ bv,
    bf16_t* __restrict__ outBase,
    const float* __restrict__ ropeC, const float* __restrict__ ropeS) {
  __shared__ bf16_t sA[4096], sB[4096];
  const int z = blockIdx.z;
  const bf16_t* Bt = WtBase + (size_t)z * Kd * N;
  const float* bias = (z == 0) ? bq : (z == 1) ? bk : bv;
  unsigned short* outp = (unsigned short*)(outBase + (size_t)z * M * N);
  const int n0 = blockIdx.x * 128, m0 = blockIdx.y * 128;
  f32x4 acc[4][4] = {};
  gemm_mainloop(xb, Bt, sA, sB, m0, n0, acc);

  const int tid = threadIdx.x, lane = tid & 63, wid = tid >> 6;
  const int l16 = lane & 15, quad = lane >> 4;
  const int wm = (wid >> 1) * 64, wn = (wid & 1) * 64;
  const int cbase = n0 + wn;          // 64-aligned -> one head per wave slab
  const int h = cbase >> 6;

  if (z < 2) {
    // Q gets 0.125 (=1/sqrt(D)) * log2(e) folded in so attention can use exp2
    const float qs = (z == 0) ? 0.18033688011112042f : 1.0f;
#pragma unroll
    for (int mi = 0; mi < 4; ++mi)
#pragma unroll
      for (int r = 0; r < 4; ++r) {
        int t = m0 + wm + mi * 16 + quad * 4 + r;
        int bb = t >> 11, s = t & (S - 1);
        size_t obase = ((size_t)(bb * H + h) * S + s) * Dh;
#pragma unroll
        for (int np = 0; np < 2; ++np) {
          int j = np * 16 + l16;
          float cc = ropeC[s * 32 + j];
          float ss = ropeS[s * 32 + j];
          float xlo = acc[mi][np][r]     + bias[cbase + j];
          float xhi = acc[mi][np + 2][r] + bias[cbase + j + 32];
          outp[obase + j]      = f2bf((xlo * cc - xhi * ss) * qs);
          outp[obase + j + 32] = f2bf((xhi * cc + xlo * ss) * qs);
        }
      }
  } else {
#pragma unroll
    for (int mi = 0; mi < 4; ++mi)
#pragma unroll
      for (int r = 0; r < 4; ++r) {
        int t = m0 + wm + mi * 16 + quad * 4 + r;
        int bb = t >> 11, s = t & (S - 1);
        size_t obase = ((size_t)(bb * H + h) * S + s) * Dh;
#pragma unroll
        for (int ni = 0; ni < 4; ++ni) {
          int d = ni * 16 + l16;
          outp[obase + d] = f2bf(acc[mi][ni][r] + bias[cbase + d]);
        }
      }
  }
}

// output GEMM: 64(m) x 128(n) tiles -> 512 blocks (2/CU)
__global__ __launch_bounds__(256, 4) void gemm_o_kernel(
    const bf16_t* __restrict__ A, const bf16_t* __restrict__ Bt,
    const float* __restrict__ bias, float* __restrict__ out) {
  __shared__ bf16_t sA[2048], sB[4096];     // 4KB A (64x32), 8KB B (128x32)
  const int n0 = blockIdx.x * 128, m0 = blockIdx.y * 64;
  const int tid = threadIdx.x, lane = tid & 63, wid = tid >> 6;
  const int l16 = lane & 15, quad = lane >> 4;
  const int wm = (wid >> 1) * 32, wn = (wid & 1) * 64;
  const int rowoff = lane >> 2, col8 = (lane & 3) * 8;
  const char* Ab = (const char*)A;
  const char* Bb = (const char*)Bt;
  char* sAc = (char*)sA;
  char* sBc = (char*)sB;
  f32x4 acc[2][4] = {};

  for (int k0 = 0; k0 < Kd; k0 += 32) {
    __syncthreads();
    async_copy16(sAc + wid * 1024,
                 Ab + ((size_t)(m0 + wid * 16 + rowoff) * Kd + k0 + col8) * 2);
    async_copy16(sBc + (wid * 2) * 1024,
                 Bb + ((size_t)(n0 + wid * 32 + rowoff) * Kd + k0 + col8) * 2);
    async_copy16(sBc + (wid * 2 + 1) * 1024,
                 Bb + ((size_t)(n0 + wid * 32 + 16 + rowoff) * Kd + k0 + col8) * 2);
    __syncthreads();
    bf16x8 af[2], bfv[4];
#pragma unroll
    for (int mi = 0; mi < 2; ++mi)
      af[mi] = *(const bf16x8*)(sA + (wm + mi * 16 + l16) * 32 + quad * 8);
#pragma unroll
    for (int ni = 0; ni < 4; ++ni)
      bfv[ni] = *(const bf16x8*)(sB + (wn + ni * 16 + l16) * 32 + quad * 8);
#pragma unroll
    for (int mi = 0; mi < 2; ++mi)
#pragma unroll
      for (int ni = 0; ni < 4; ++ni)
        acc[mi][ni] = __builtin_amdgcn_mfma_f32_16x16x32_bf16(af[mi], bfv[ni], acc[mi][ni], 0, 0, 0);
  }
#pragma unroll
  for (int mi = 0; mi < 2; ++mi)
#pragma unroll
    for (int r = 0; r < 4; ++r) {
      int t = m0 + wm + mi * 16 + quad * 4 + r;
#pragma unroll
      for (int ni = 0; ni < 4; ++ni) {
        int c = n0 + wn + ni * 16 + l16;
        out[(size_t)t * N + c] = acc[mi][ni][r] + bias[c];
      }
    }
}

// ---------------- flash attention: barrier-free wave streaming ----------------
// One wave owns 32 q rows and streams its full causal key range in 64-key
// tiles, loading K and V^T fragments DIRECTLY from global (L1-line-friendly:
// adjacent c-iterations consume the same 64B lines). No __syncthreads anywhere;
// 2048 independent waves (all co-resident) hide latency. Fixed-m base-2 softmax
// (scale folded into Q) makes output a pure sum over keys. LDS only holds the
// per-wave P bounce (C-layout -> A-operand).
__global__ __launch_bounds__(256) void attn_kernel(
    const bf16_t* __restrict__ Q, const bf16_t* __restrict__ Kb,
    const bf16_t* __restrict__ Vt, const int* __restrict__ mask,
    bf16_t* __restrict__ ctx) {
  __shared__ unsigned short sP[4][32 * 72];    // per-wave P [q][key], stride 72

  const int tid = threadIdx.x, lane = tid & 63, wid = tid >> 6;
  const int l32 = lane & 31, half = lane >> 5;

  const int qt = 63 - (blockIdx.x >> 3);       // 0..63, longest waves first
  const int bh = ((blockIdx.x & 7) << 2) | wid;
  const int b  = bh >> 4;
  const int qw = qt * 32;

  const bf16_t* Qp = Q  + ((size_t)bh * S + qw) * Dh;
  const bf16_t* Kp = Kb + (size_t)bh * S * Dh;
  const bf16_t* Vp = Vt + (size_t)bh * Dh * S;
  const int*    mp = mask + b * S;

  // Q as B-operand of 32x32x16: B[k=c*16+half*8+j][n=q=l32]
  bf16x8 qf[4];
#pragma unroll
  for (int c = 0; c < 4; ++c)
    qf[c] = *(const bf16x8*)(Qp + l32 * Dh + c * 16 + half * 8);

  f32x16 cacc[2] = {};
  float lsum = 0.f;
  const int qcol = qw + l32;
  const int niter = (qt >> 1) + 1;
  unsigned short* pb = &sP[wid][0];

  for (int kt = 0; kt < niter; ++kt) {
    const int kb = kt * 64;
    int mk = mp[kb + lane];

    // S^T = K.Q^T : A-frag K[m=key=g*32+l32][k=c*16+half*8+j] direct from global
    f32x16 st[2] = {};
#pragma unroll
    for (int c = 0; c < 4; ++c) {
      bf16x8 kf0 = *(const bf16x8*)(Kp + (size_t)(kb + l32) * Dh + c * 16 + half * 8);
      bf16x8 kf1 = *(const bf16x8*)(Kp + (size_t)(kb + 32 + l32) * Dh + c * 16 + half * 8);
      st[0] = __builtin_amdgcn_mfma_f32_32x32x16_bf16(kf0, qf[c], st[0], 0, 0, 0);
      st[1] = __builtin_amdgcn_mfma_f32_32x32x16_bf16(kf1, qf[c], st[1], 0, 0, 0);
    }

    // padding mask (wave-uniform skip when all alive)
    unsigned long long dm = __ballot(mk == 0);
    if (dm) {
#pragma unroll
      for (int g = 0; g < 2; ++g)
#pragma unroll
        for (int r = 0; r < 16; ++r) {
          int krow = g * 32 + (r & 3) + 8 * (r >> 2) + 4 * half;
          if ((dm >> krow) & 1ull) st[g][r] = -1e30f;
        }
    }
    // causal mask: only the diagonal (last) tile
    if (kt == niter - 1) {
#pragma unroll
      for (int g = 0; g < 2; ++g)
#pragma unroll
        for (int r = 0; r < 16; ++r) {
          int key = kb + g * 32 + (r & 3) + 8 * (r >> 2) + 4 * half;
          if (key > qcol) st[g][r] = -1e30f;
        }
    }

    // p = exp2(s) (fixed m), accumulate l, pack P[q][key] to per-wave LDS
#pragma unroll
    for (int g = 0; g < 2; ++g)
#pragma unroll
      for (int rg = 0; rg < 4; ++rg) {
        float e0 = exp2f(st[g][rg * 4 + 0]);
        float e1 = exp2f(st[g][rg * 4 + 1]);
        float e2 = exp2f(st[g][rg * 4 + 2]);
        float e3 = exp2f(st[g][rg * 4 + 3]);
        lsum += (e0 + e1) + (e2 + e3);
        bf16x4 pk = { (bf16_t)e0, (bf16_t)e1, (bf16_t)e2, (bf16_t)e3 };
        *(bf16x4*)&pb[l32 * 72 + g * 32 + rg * 8 + half * 4] = pk;
      }

    // P as A-operand: A[m=q=l32][k=key=c*16+half*8+j]
    bf16x8 pf[4];
#pragma unroll
    for (int c = 0; c < 4; ++c)
      pf[c] = *(const bf16x8*)((const bf16_t*)(const void*)pb + l32 * 72 + c * 16 + half * 8);

    // ctx[q][d] += P.V ; B-frag V[k=key=c*16+half*8+j][n=d=dg*32+l32] from V^T
#pragma unroll
    for (int c = 0; c < 4; ++c) {
      bf16x8 vf0 = *(const bf16x8*)(Vp + (size_t)l32 * S + kb + c * 16 + half * 8);
      bf16x8 vf1 = *(const bf16x8*)(Vp + (size_t)(32 + l32) * S + kb + c * 16 + half * 8);
      cacc[0] = __builtin_amdgcn_mfma_f32_32x32x16_bf16(pf[c], vf0, cacc[0], 0, 0, 0);
      cacc[1] = __builtin_amdgcn_mfma_f32_32x32x16_bf16(pf[c], vf1, cacc[1], 0, 0, 0);
    }
  }

  // l: lanes i and i+32 hold partials for q=i
  lsum += __shfl_xor(lsum, 32);
  float iv = 1.0f / lsum;
  // redistribute inv from per-lane(q) to per-row(q) via per-wave LDS
  float* ib = (float*)(void*)pb;
  if (half == 0) ib[l32] = iv;
  f32x4 ivq[4];
#pragma unroll
  for (int rg = 0; rg < 4; ++rg)
    ivq[rg] = *(const f32x4*)&ib[rg * 8 + half * 4];

  unsigned short* cp = (unsigned short*)ctx;
  const size_t base = ((size_t)(b * S + qw)) * N + (size_t)(bh & 15) * 64;
#pragma unroll
  for (int dg = 0; dg < 2; ++dg)
#pragma unroll
    for (int r = 0; r < 16; ++r) {
      int row = (r & 3) + 8 * (r >> 2) + 4 * half;
      cp[base + (size_t)row * N + dg * 32 + l32] = f2bf(cacc[dg][r] * ivq[r >> 2][r & 3]);
    }
}

// ---------------- launcher ----------------

extern "C" void kernel_launch(void* const* d_in, const int* in_sizes, int n_in,
                              void* d_out, int out_size, void* d_ws, size_t ws_size,
                              hipStream_t stream) {
  const float* x  = (const float*)d_in[0];
  const int*  msk = (const int*)d_in[1];
  const float* Wq = (const float*)d_in[2];
  const float* bq = (const float*)d_in[3];
  const float* Wk = (const float*)d_in[4];
  const float* bk = (const float*)d_in[5];
  const float* Wv = (const float*)d_in[6];
  const float* bv = (const float*)d_in[7];
  const float* Wo = (const float*)d_in[8];
  const float* bo = (const float*)d_in[9];
  float* out = (float*)d_out;
  (void)in_sizes; (void)n_in; (void)out_size; (void)ws_size;

  char* ws = (char*)d_ws;
  bf16_t* xb   = (bf16_t*)(ws);                      // 8 MB  [4096][1024]
  bf16_t* WT   = (bf16_t*)(ws + (8u  << 20));        // 8 MB  4 x [1024][1024] (N-major)
  bf16_t* qkv  = (bf16_t*)(ws + (16u << 20));        // 24 MB Q,K,V each [B,H,S,D]
  bf16_t* Qb   = qkv;
  bf16_t* Kbuf = qkv + (size_t)1 * M * N;
  bf16_t* Vb   = qkv + (size_t)2 * M * N;
  bf16_t* Vt   = xb;                                  // alias: xb dead after QKV GEMM
  bf16_t* ctx  = Vb;                                  // alias: V[B,H,S,D] dead after vtrans
  float* ropeC = (float*)(ws + (40u << 20));          // 256 KB
  float* ropeS = ropeC + (size_t)S * 32;              // 256 KB

  prep_kernel<<<5376, 256, 0, stream>>>(x, xb, Wq, Wk, Wv, Wo, WT, ropeC, ropeS);
  gemm_qkv_kernel<<<dim3(8, 32, 3), 256, 0, stream>>>(xb, WT, bq, bk, bv, qkv, ropeC, ropeS);
  vtrans_kernel<<<dim3(32, 32), 256, 0, stream>>>(Vb, Vt);
  attn_kernel<<<512, 256, 0, stream>>>(Qb, Kbuf, Vt, msk, ctx);
  gemm_o_kernel<<<dim3(8, 64), 256, 0, stream>>>(ctx, WT + (size_t)3 * Kd * N, bo, out);
}

// Round 6
// 204.869 us; speedup vs baseline: 1.1832x; 1.1832x over previous
//
#include <hip/hip_runtime.h>
#include <cstdint>
#include <cstddef>

#define DEVI __device__ __forceinline__

typedef __bf16 bf16_t;
typedef __bf16 bf16x4 __attribute__((ext_vector_type(4)));
typedef __bf16 bf16x8 __attribute__((ext_vector_type(8)));
typedef float  f32x4  __attribute__((ext_vector_type(4)));
typedef unsigned short u16x4 __attribute__((ext_vector_type(4)));

static constexpr int Bz = 2, S = 2048, E = 1024, H = 16, Dh = 64;
static constexpr int M  = Bz * S;   // 4096 tokens
static constexpr int N  = H * Dh;   // 1024
static constexpr int Kd = E;        // 1024

DEVI unsigned short f2bf(float f) {
  unsigned u = __builtin_bit_cast(unsigned, f);
  return (unsigned short)((u + 0x7fffu + ((u >> 16) & 1u)) >> 16);
}

DEVI void async_copy16(void* lds, const void* g) {
  __builtin_amdgcn_global_load_lds((__attribute__((address_space(1))) void*)(g),
                                   (__attribute__((address_space(3))) void*)(lds), 16, 0, 0);
}

// ---------------- fused prep: convx | wtrans | rope table ----------------
__global__ void prep_kernel(const float* __restrict__ x, bf16_t* __restrict__ xb,
                            const float* __restrict__ Wq, const float* __restrict__ Wk,
                            const float* __restrict__ Wv, const float* __restrict__ Wo,
                            bf16_t* __restrict__ WtBase,
                            float* __restrict__ ropeC, float* __restrict__ ropeS) {
  __shared__ unsigned short tile[64][68];
  const int blk = blockIdx.x, tid = threadIdx.x;
  if (blk < 4096) {
    int i = blk * 256 + tid;
    float4 v = ((const float4*)x)[i];
    u16x4 o = { f2bf(v.x), f2bf(v.y), f2bf(v.z), f2bf(v.w) };
    ((u16x4*)xb)[i] = o;
  } else if (blk < 5120) {
    const int i = blk - 4096;
    const int z = i >> 8, rest = i & 255;
    const int n0 = (rest & 15) * 64, k0 = (rest >> 4) * 64;
    const float* W = (z == 0) ? Wq : (z == 1) ? Wk : (z == 2) ? Wv : Wo;
    unsigned short* T = (unsigned short*)(WtBase + (size_t)z * Kd * N);
    for (int e = tid; e < 1024; e += 256) {
      int r = e >> 4, c4 = (e & 15) * 4;
      float4 v = *(const float4*)(W + (size_t)(k0 + r) * N + n0 + c4);
      u16x4 o = { f2bf(v.x), f2bf(v.y), f2bf(v.z), f2bf(v.w) };
      *(u16x4*)&tile[r][c4] = o;
    }
    __syncthreads();
    for (int e = tid; e < 1024; e += 256) {
      int r = e >> 4, c4 = (e & 15) * 4;
      u16x4 o = { tile[c4][r], tile[c4 + 1][r], tile[c4 + 2][r], tile[c4 + 3][r] };
      *(u16x4*)&T[(size_t)(n0 + r) * Kd + k0 + c4] = o;
    }
  } else {
    int i = (blk - 5120) * 256 + tid;
    int pos = i >> 5, j = i & 31;
    float inv = exp2f(-(float)j * 0.41524101186092029f);   // log2(10000)/32
    float ang = (float)pos * inv;
    ropeC[i] = cosf(ang);
    ropeS[i] = sinf(ang);
  }
}

// ---------------- GEMM core (128x128 tile, BK=32, global_load_lds) ----------------

DEVI void gemm_mainloop(const bf16_t* __restrict__ A, const bf16_t* __restrict__ Bt,
                        bf16_t* sA, bf16_t* sB, int m0, int n0, f32x4 (&acc)[4][4]) {
  const int tid  = threadIdx.x;
  const int lane = tid & 63;
  const int wid  = tid >> 6;
  const int l16  = lane & 15;
  const int quad = lane >> 4;
  const int wm = (wid >> 1) * 64;
  const int wn = (wid & 1) * 64;
  const int o0 = wid * 2048 + lane * 16;   // byte offset within 8KB tile
  const int o1 = o0 + 1024;
  const int r0 = o0 >> 6, c0 = o0 & 63;
  const int r1 = o1 >> 6, c1 = o1 & 63;
  const char* Ab = (const char*)A;
  const char* Bb = (const char*)Bt;
  char* sAc = (char*)sA;
  char* sBc = (char*)sB;

  for (int k0 = 0; k0 < Kd; k0 += 32) {
    __syncthreads();
    async_copy16(sAc + wid * 2048,        Ab + ((size_t)(m0 + r0) * Kd + k0) * 2 + c0);
    async_copy16(sAc + wid * 2048 + 1024, Ab + ((size_t)(m0 + r1) * Kd + k0) * 2 + c1);
    async_copy16(sBc + wid * 2048,        Bb + ((size_t)(n0 + r0) * Kd + k0) * 2 + c0);
    async_copy16(sBc + wid * 2048 + 1024, Bb + ((size_t)(n0 + r1) * Kd + k0) * 2 + c1);
    __syncthreads();
    bf16x8 af[4], bfv[4];
#pragma unroll
    for (int mi = 0; mi < 4; ++mi)
      af[mi] = *(const bf16x8*)(sA + (wm + mi * 16 + l16) * 32 + quad * 8);
#pragma unroll
    for (int ni = 0; ni < 4; ++ni)
      bfv[ni] = *(const bf16x8*)(sB + (wn + ni * 16 + l16) * 32 + quad * 8);
#pragma unroll
    for (int mi = 0; mi < 4; ++mi)
#pragma unroll
      for (int ni = 0; ni < 4; ++ni)
        acc[mi][ni] = __builtin_amdgcn_mfma_f32_16x16x32_bf16(af[mi], bfv[ni], acc[mi][ni], 0, 0, 0);
  }
}

// z = 0:Q(RoPE+scale) 1:K(RoPE) -> [B,H,S,D]; z = 2:V -> TRANSPOSED [B,H,D,S]
__global__ __launch_bounds__(256, 3) void gemm_qkv_kernel(
    const bf16_t* __restrict__ xb, const bf16_t* __restrict__ WtBase,
    const float* __restrict__ bq, const float* __restrict__ bk, const float* __restrict__ bv,
    bf16_t* __restrict__ outBase, bf16_t* __restrict__ Vt,
    const float* __restrict__ ropeC, const float* __restrict__ ropeS) {
  __shared__ bf16_t sM[8192];               // mainloop: sA | sB ; epilogue: V^T tile
  const int z = blockIdx.z;
  const bf16_t* Bt = WtBase + (size_t)z * Kd * N;
  const float* bias = (z == 0) ? bq : (z == 1) ? bk : bv;
  const int n0 = blockIdx.x * 128, m0 = blockIdx.y * 128;
  f32x4 acc[4][4] = {};
  gemm_mainloop(xb, Bt, sM, sM + 4096, m0, n0, acc);

  const int tid = threadIdx.x, lane = tid & 63, wid = tid >> 6;
  const int l16 = lane & 15, quad = lane >> 4;
  const int wm = (wid >> 1) * 64, wn = (wid & 1) * 64;
  const int cbase = n0 + wn;          // 64-aligned -> one head per wave slab
  const int h = cbase >> 6;

  if (z < 2) {
    unsigned short* outp = (unsigned short*)(outBase + (size_t)z * M * N);
    // Q gets 0.125 (=1/sqrt(D)) * log2(e) folded in so attention can use exp2
    const float qs = (z == 0) ? 0.18033688011112042f : 1.0f;
#pragma unroll
    for (int mi = 0; mi < 4; ++mi)
#pragma unroll
      for (int r = 0; r < 4; ++r) {
        int t = m0 + wm + mi * 16 + quad * 4 + r;
        int bb = t >> 11, s = t & (S - 1);
        size_t obase = ((size_t)(bb * H + h) * S + s) * Dh;
#pragma unroll
        for (int np = 0; np < 2; ++np) {
          int j = np * 16 + l16;
          float cc = ropeC[s * 32 + j];
          float ss = ropeS[s * 32 + j];
          float xlo = acc[mi][np][r]     + bias[cbase + j];
          float xhi = acc[mi][np + 2][r] + bias[cbase + j + 32];
          outp[obase + j]      = f2bf((xlo * cc - xhi * ss) * qs);
          outp[obase + j + 32] = f2bf((xhi * cc + xlo * ss) * qs);
        }
      }
  } else {
    // fused V-transpose: acc -> LDS [dloc][t] (stride 136) -> coalesced Vt[B,H,D,S]
    const int bb = m0 >> 11, s0 = m0 & (S - 1);
    const int head0 = n0 >> 6;
    const int myh = wid & 1;             // this wave's head half (== wn/64)
    for (int hh = 0; hh < 2; ++hh)
      for (int dq = 0; dq < 2; ++dq) {
        __syncthreads();                 // LDS free / previous pass consumed
        if (myh == hh) {
#pragma unroll
          for (int ni2 = 0; ni2 < 2; ++ni2) {
            int ni = dq * 2 + ni2;
            int dloc = ni2 * 16 + l16;
            float bv_ = bias[cbase + ni * 16 + l16];
#pragma unroll
            for (int mi = 0; mi < 4; ++mi)
#pragma unroll
              for (int r = 0; r < 4; ++r) {
                int tloc = wm + mi * 16 + quad * 4 + r;
                sM[dloc * 136 + tloc] = (bf16_t)(acc[mi][ni][r] + bv_);
              }
          }
        }
        __syncthreads();
#pragma unroll
        for (int rep = 0; rep < 2; ++rep) {
          int cidx = rep * 256 + tid;    // 512 chunks of 16B = 32d x 128t
          int dloc = cidx >> 4, chunk = cidx & 15;
          bf16x8 v = *(const bf16x8*)&sM[dloc * 136 + chunk * 8];
          size_t off = ((size_t)(bb * H + head0 + hh) * Dh + dq * 32 + dloc) * S + s0 + chunk * 8;
          *(bf16x8*)(Vt + off) = v;
        }
      }
  }
}

// output GEMM: 64(m) x 128(n) tiles -> 512 blocks (2/CU)
__global__ __launch_bounds__(256, 4) void gemm_o_kernel(
    const bf16_t* __restrict__ A, const bf16_t* __restrict__ Bt,
    const float* __restrict__ bias, float* __restrict__ out) {
  __shared__ bf16_t sA[2048], sB[4096];     // 4KB A (64x32), 8KB B (128x32)
  const int n0 = blockIdx.x * 128, m0 = blockIdx.y * 64;
  const int tid = threadIdx.x, lane = tid & 63, wid = tid >> 6;
  const int l16 = lane & 15, quad = lane >> 4;
  const int wm = (wid >> 1) * 32, wn = (wid & 1) * 64;
  const int rowoff = lane >> 2, col8 = (lane & 3) * 8;
  const char* Ab = (const char*)A;
  const char* Bb = (const char*)Bt;
  char* sAc = (char*)sA;
  char* sBc = (char*)sB;
  f32x4 acc[2][4] = {};

  for (int k0 = 0; k0 < Kd; k0 += 32) {
    __syncthreads();
    async_copy16(sAc + wid * 1024,
                 Ab + ((size_t)(m0 + wid * 16 + rowoff) * Kd + k0 + col8) * 2);
    async_copy16(sBc + (wid * 2) * 1024,
                 Bb + ((size_t)(n0 + wid * 32 + rowoff) * Kd + k0 + col8) * 2);
    async_copy16(sBc + (wid * 2 + 1) * 1024,
                 Bb + ((size_t)(n0 + wid * 32 + 16 + rowoff) * Kd + k0 + col8) * 2);
    __syncthreads();
    bf16x8 af[2], bfv[4];
#pragma unroll
    for (int mi = 0; mi < 2; ++mi)
      af[mi] = *(const bf16x8*)(sA + (wm + mi * 16 + l16) * 32 + quad * 8);
#pragma unroll
    for (int ni = 0; ni < 4; ++ni)
      bfv[ni] = *(const bf16x8*)(sB + (wn + ni * 16 + l16) * 32 + quad * 8);
#pragma unroll
    for (int mi = 0; mi < 2; ++mi)
#pragma unroll
      for (int ni = 0; ni < 4; ++ni)
        acc[mi][ni] = __builtin_amdgcn_mfma_f32_16x16x32_bf16(af[mi], bfv[ni], acc[mi][ni], 0, 0, 0);
  }
#pragma unroll
  for (int mi = 0; mi < 2; ++mi)
#pragma unroll
    for (int r = 0; r < 4; ++r) {
      int t = m0 + wm + mi * 16 + quad * 4 + r;
#pragma unroll
      for (int ni = 0; ni < 4; ++ni) {
        int c = n0 + wn + ni * 16 + l16;
        out[(size_t)t * N + c] = acc[mi][ni][r] + bias[c];
      }
    }
}

// ---------------- flash attention ----------------
// r3 structure (4 waves share LDS K/V tiles, 1024 blocks, 16x16 MFMA, fixed-m
// base-2 softmax) with the ONE defect fixed: 64-key tiles DOUBLE-BUFFERED with
// a single barrier per iteration — prefetch of tile kt+1 is issued right after
// the barrier and a full compute phase covers its latency (r3 exposed the full
// staging latency at its second barrier every iteration). Mask load issued
// BEFORE the prefetch so its waitcnt doesn't drain the prefetch queue.
__global__ __launch_bounds__(256, 3) void attn_kernel(
    const bf16_t* __restrict__ Q, const bf16_t* __restrict__ Kb,
    const bf16_t* __restrict__ Vt, const int* __restrict__ mask,
    bf16_t* __restrict__ ctx) {
  __shared__ bf16_t sK[2][4096];               // 2 x 8KB: sections (g*2+ch)*512
  __shared__ bf16_t sV[2][4096];               // 2 x 8KB: sections (dt*2+kc)*512
  __shared__ unsigned short sP[4][16 * 72];    // per-wave P^T bounce, stride 72

  const int tid = threadIdx.x, lane = tid & 63, wid = tid >> 6;
  const int l16 = lane & 15, quad = lane >> 4;

  const int idx = blockIdx.x;
  const int qb  = 31 - (idx >> 5);             // longest blocks launch first
  const int bh  = idx & 31;
  const int b   = bh >> 4;
  const int q0  = qb * 64;
  const int qw  = q0 + wid * 16;

  const bf16_t* Qp = Q + ((size_t)bh * S + qw) * Dh;
  const char*   Kg = (const char*)(Kb + (size_t)bh * S * Dh);
  const char*   Vg = (const char*)(Vt + (size_t)bh * Dh * S);
  const int*    mp = mask + b * S;

  // Q as B-operand: B[k=d=quad*8+j][n=q=l16]
  bf16x8 qf0 = *(const bf16x8*)(Qp + l16 * Dh + quad * 8);
  bf16x8 qf1 = *(const bf16x8*)(Qp + l16 * Dh + 32 + quad * 8);

  // wave wid stages K sections {2wid (ch0), 2wid+1 (ch1)} (g = wid) and V
  // sections {2wid (kc0), 2wid+1 (kc1)} (dt = wid)
  const size_t kOff0 = ((size_t)(wid * 16 + l16) * Dh + quad * 8) * 2;
  const size_t kOff1 = kOff0 + 64;             // +32 elements (d half 1)
  const size_t vOff0 = ((size_t)(wid * 16 + l16) * S + quad * 8) * 2;
  const size_t vOff1 = vOff0 + 64;             // +32 keys
  char* sKc = (char*)sK;
  char* sVc = (char*)sV;

  auto stage = [&](int buf, int kt) {
    size_t kbK = (size_t)kt * 64 * Dh * 2;
    size_t kbV = (size_t)kt * 64 * 2;
    async_copy16(sKc + buf * 8192 + wid * 2048,        Kg + kbK + kOff0);
    async_copy16(sKc + buf * 8192 + wid * 2048 + 1024, Kg + kbK + kOff1);
    async_copy16(sVc + buf * 8192 + wid * 2048,        Vg + kbV + vOff0);
    async_copy16(sVc + buf * 8192 + wid * 2048 + 1024, Vg + kbV + vOff1);
  };

  f32x4 acc[4] = {};
  float lsum = 0.f;
  const int qcol = qw + l16;
  const int niter = qb + 1;
  unsigned short* pb = &sP[wid][0];

  stage(0, 0);
  for (int kt = 0; kt < niter; ++kt) {
    const int kb = kt * 64;
    __syncthreads();                           // buf[kt&1] staged; prev reads done
    int mk = mp[kb + lane];                    // issue BEFORE prefetch (waitcnt)
    if (kt + 1 < niter) stage((kt + 1) & 1, kt + 1);
    const bf16_t* kbuf = &sK[kt & 1][0];
    const bf16_t* vbuf = &sV[kt & 1][0];

    // S^T = K.Q^T : 4 key groups of 16
    f32x4 st[4];
#pragma unroll
    for (int g = 0; g < 4; ++g) {
      bf16x8 kf0 = *(const bf16x8*)(kbuf + (g * 2 + 0) * 512 + lane * 8);
      bf16x8 kf1 = *(const bf16x8*)(kbuf + (g * 2 + 1) * 512 + lane * 8);
      f32x4 z = {};
      z = __builtin_amdgcn_mfma_f32_16x16x32_bf16(kf0, qf0, z, 0, 0, 0);
      z = __builtin_amdgcn_mfma_f32_16x16x32_bf16(kf1, qf1, z, 0, 0, 0);
      st[g] = z;                               // S^T[key=g*16+quad*4+r][q=l16]
    }

    // padding mask (wave-uniform skip when all alive)
    unsigned long long dm = __ballot(mk == 0);
    if (dm) {
#pragma unroll
      for (int g = 0; g < 4; ++g)
#pragma unroll
        for (int r = 0; r < 4; ++r)
          if ((dm >> (g * 16 + quad * 4 + r)) & 1ull) st[g][r] = -1e30f;
    }
    // causal mask: only the diagonal (last) tile
    if (kt == niter - 1) {
#pragma unroll
      for (int g = 0; g < 4; ++g)
#pragma unroll
        for (int r = 0; r < 4; ++r)
          if (kb + g * 16 + quad * 4 + r > qcol) st[g][r] = -1e30f;
    }

    // p = exp2(s) (fixed m), accumulate l, pack P^T into per-wave LDS
#pragma unroll
    for (int g = 0; g < 4; ++g) {
      float e0 = exp2f(st[g][0]), e1 = exp2f(st[g][1]);
      float e2 = exp2f(st[g][2]), e3 = exp2f(st[g][3]);
      lsum += (e0 + e1) + (e2 + e3);
      bf16x4 pk = { (bf16_t)e0, (bf16_t)e1, (bf16_t)e2, (bf16_t)e3 };
      *(bf16x4*)&pb[l16 * 72 + g * 16 + quad * 4] = pk;
    }
    bf16x8 pf0 = *(const bf16x8*)((const bf16_t*)(const void*)pb + l16 * 72 + quad * 8);
    bf16x8 pf1 = *(const bf16x8*)((const bf16_t*)(const void*)pb + l16 * 72 + 32 + quad * 8);

    // ctx^T += V^T.P^T
#pragma unroll
    for (int dt = 0; dt < 4; ++dt) {
      bf16x8 vf0 = *(const bf16x8*)(vbuf + (dt * 2 + 0) * 512 + lane * 8);
      bf16x8 vf1 = *(const bf16x8*)(vbuf + (dt * 2 + 1) * 512 + lane * 8);
      acc[dt] = __builtin_amdgcn_mfma_f32_16x16x32_bf16(vf0, pf0, acc[dt], 0, 0, 0);
      acc[dt] = __builtin_amdgcn_mfma_f32_16x16x32_bf16(vf1, pf1, acc[dt], 0, 0, 0);
    }
  }

  lsum += __shfl_xor(lsum, 16);
  lsum += __shfl_xor(lsum, 32);
  float inv = 1.0f / lsum;
  unsigned short* cp = (unsigned short*)ctx;
  size_t trow = ((size_t)(b * S + qw + l16)) * N + (size_t)(bh & 15) * Dh;
#pragma unroll
  for (int dt = 0; dt < 4; ++dt) {
    u16x4 o = { f2bf(acc[dt][0] * inv), f2bf(acc[dt][1] * inv),
                f2bf(acc[dt][2] * inv), f2bf(acc[dt][3] * inv) };
    *(u16x4*)&cp[trow + dt * 16 + quad * 4] = o;
  }
}

// ---------------- launcher ----------------

extern "C" void kernel_launch(void* const* d_in, const int* in_sizes, int n_in,
                              void* d_out, int out_size, void* d_ws, size_t ws_size,
                              hipStream_t stream) {
  const float* x  = (const float*)d_in[0];
  const int*  msk = (const int*)d_in[1];
  const float* Wq = (const float*)d_in[2];
  const float* bq = (const float*)d_in[3];
  const float* Wk = (const float*)d_in[4];
  const float* bk = (const float*)d_in[5];
  const float* Wv = (const float*)d_in[6];
  const float* bv = (const float*)d_in[7];
  const float* Wo = (const float*)d_in[8];
  const float* bo = (const float*)d_in[9];
  float* out = (float*)d_out;
  (void)in_sizes; (void)n_in; (void)out_size; (void)ws_size;

  char* ws = (char*)d_ws;
  bf16_t* xb   = (bf16_t*)(ws);                      // 8 MB  [4096][1024]
  bf16_t* WT   = (bf16_t*)(ws + (8u  << 20));        // 8 MB  4 x [1024][1024] (N-major)
  bf16_t* Qb   = (bf16_t*)(ws + (16u << 20));        // 8 MB  [B,H,S,D]
  bf16_t* Kbuf = (bf16_t*)(ws + (24u << 20));        // 8 MB  [B,H,S,D]
  bf16_t* Vt   = (bf16_t*)(ws + (32u << 20));        // 8 MB  [B,H,D,S] (written by gemm_qkv z=2)
  float* ropeC = (float*)(ws + (40u << 20));         // 256 KB
  float* ropeS = ropeC + (size_t)S * 32;             // 256 KB
  bf16_t* ctx  = (bf16_t*)(ws + (41u << 20));        // 8 MB  [B,S,H*D]

  prep_kernel<<<5376, 256, 0, stream>>>(x, xb, Wq, Wk, Wv, Wo, WT, ropeC, ropeS);
  gemm_qkv_kernel<<<dim3(8, 32, 3), 256, 0, stream>>>(xb, WT, bq, bk, bv, Qb, Vt, ropeC, ropeS);
  attn_kernel<<<1024, 256, 0, stream>>>(Qb, Kbuf, Vt, msk, ctx);
  gemm_o_kernel<<<dim3(8, 64), 256, 0, stream>>>(ctx, WT + (size_t)3 * Kd * N, bo, out);
}